// Round 9
// baseline (156.190 us; speedup 1.0000x reference)
//
#include <hip/hip_runtime.h>

// KL(p||q) for diagonal Gaussians, reduced to a single scalar:
// out = (0.5/B) * sum_{b,d} [ (qlv-plv) + exp(plv-qlv) + (pmu-qmu)^2*exp(-qlv) - 1 ]
//
// Roofline context: five structurally different stage-1 variants (grid-stride,
// 16-upfront regs, NT, contiguous windows, LDS-DMA) all plateau at 36-42us =
// 3.2-3.7 TB/s delivered read. Machine refs: D2D copy 6.29 TB/s combined
// (read stream ~3.15 TB/s), pure-write fill 6.6 TB/s. We are at the streaming
// read ceiling. This version = round-6's best memory structure (contiguous
// 16KB windows, 16 NT loads up-front) + stage-2 fused via one atomicAdd per
// block (measured free at 2048 blocks: rounds 1 vs 3), saving the second
// kernel launch.

typedef float vf4 __attribute__((ext_vector_type(4)));

__device__ __forceinline__ float kl4(const vf4 a, const vf4 b,
                                     const vf4 c, const vf4 d) {
  float acc = 0.0f, lr, dx;
  #pragma unroll
  for (int k = 0; k < 4; ++k) {
    lr = d[k] - b[k];
    dx = a[k] - c[k];
    acc += lr + __expf(-lr) + dx * dx * __expf(-d[k]) - 1.0f;
  }
  return acc;
}

__device__ __forceinline__ float block_reduce_256(float acc) {
  #pragma unroll
  for (int off = 32; off > 0; off >>= 1)
    acc += __shfl_down(acc, off, 64);
  __shared__ float sm[4];
  const int lane = threadIdx.x & 63;
  const int wid  = threadIdx.x >> 6;
  if (lane == 0) sm[wid] = acc;
  __syncthreads();
  return sm[0] + sm[1] + sm[2] + sm[3];
}

// 2048 blocks x 256 threads. Block b owns vf4 range [b*1024, (b+1)*1024) in
// each array (16KB contiguous window); thread reads 4 tiers at +256 vf4.
// All 16 loads issued before any compute (nontemporal). One atomicAdd per
// block folds the partial into d_out.
__global__ __launch_bounds__(256) void kl_reduce_kernel(
    const vf4* __restrict__ pmu,
    const vf4* __restrict__ plv,
    const vf4* __restrict__ qmu,
    const vf4* __restrict__ qlv,
    float* __restrict__ out, float scale) {
  const int base = blockIdx.x * 1024 + threadIdx.x;

  vf4 A[4], Bv[4], C[4], Dv[4];
  #pragma unroll
  for (int t = 0; t < 4; ++t) {
    const int i = base + t * 256;
    A[t]  = __builtin_nontemporal_load(&pmu[i]);
    Bv[t] = __builtin_nontemporal_load(&plv[i]);
    C[t]  = __builtin_nontemporal_load(&qmu[i]);
    Dv[t] = __builtin_nontemporal_load(&qlv[i]);
  }

  float acc = 0.0f;
  #pragma unroll
  for (int t = 0; t < 4; ++t)
    acc += kl4(A[t], Bv[t], C[t], Dv[t]);

  const float blocksum = block_reduce_256(acc);
  if (threadIdx.x == 0) atomicAdd(out, blocksum * scale);
}

extern "C" void kernel_launch(void* const* d_in, const int* in_sizes, int n_in,
                              void* d_out, int out_size, void* d_ws, size_t ws_size,
                              hipStream_t stream) {
  const vf4* pmu = (const vf4*)d_in[0];
  const vf4* plv = (const vf4*)d_in[1];
  const vf4* qmu = (const vf4*)d_in[2];
  const vf4* qlv = (const vf4*)d_in[3];
  float* out = (float*)d_out;

  const int B = 16384;
  const float scale = 0.5f / (float)B;

  // d_out is poisoned to 0xAA before every launch; zero it on-stream.
  hipMemsetAsync(d_out, 0, sizeof(float), stream);

  const int block = 256;
  const int grid = 2048;                // 2048 windows x 1024 vf4 = 2M vf4/array
  kl_reduce_kernel<<<grid, block, 0, stream>>>(pmu, plv, qmu, qlv, out, scale);
}

// Round 10
// 142.474 us; speedup vs baseline: 1.0963x; 1.0963x over previous
//
#include <hip/hip_runtime.h>

// KL(p||q) for diagonal Gaussians, reduced to a single scalar:
// out = (0.5/B) * sum_{b,d} [ (qlv-plv) + exp(plv-qlv) + (pmu-qmu)^2*exp(-qlv) - 1 ]
//
// FINAL (round-6 structure, measured best: bench 142.7us, stage-1 ~36us).
// Roofline: six structurally diverse stage-1 variants (grid-stride,
// SW-pipeline, 16-upfront regs, NT, contiguous windows, XCD swizzle,
// LDS-DMA) all plateau at 36-42us = 3.2-3.7 TB/s delivered read — at/above
// the machine's D2D-copy read stream (6.29 TB/s combined => ~3.15 TB/s per
// direction). Bytes are irreducible (134 MB fp32, zero reuse, scalar out).
// Fused-atomic + memset variant (round 9) regressed: keep two kernels.

typedef float vf4 __attribute__((ext_vector_type(4)));

__device__ __forceinline__ float kl4(const vf4 a, const vf4 b,
                                     const vf4 c, const vf4 d) {
  float acc = 0.0f, lr, dx;
  #pragma unroll
  for (int k = 0; k < 4; ++k) {
    lr = d[k] - b[k];
    dx = a[k] - c[k];
    acc += lr + __expf(-lr) + dx * dx * __expf(-d[k]) - 1.0f;
  }
  return acc;
}

__device__ __forceinline__ float block_reduce_256(float acc) {
  #pragma unroll
  for (int off = 32; off > 0; off >>= 1)
    acc += __shfl_down(acc, off, 64);
  __shared__ float sm[4];
  const int lane = threadIdx.x & 63;
  const int wid  = threadIdx.x >> 6;
  if (lane == 0) sm[wid] = acc;
  __syncthreads();
  return sm[0] + sm[1] + sm[2] + sm[3];
}

// Stage 1: 2048 blocks x 256 threads. Block b owns vf4 range
// [b*1024, (b+1)*1024) in each array (16KB contiguous window); thread reads
// tiers at +256 within the window. All 16 loads issued before any compute.
__global__ __launch_bounds__(256) void kl_partial_kernel(
    const vf4* __restrict__ pmu,
    const vf4* __restrict__ plv,
    const vf4* __restrict__ qmu,
    const vf4* __restrict__ qlv,
    float* __restrict__ partials) {
  const int base = blockIdx.x * 1024 + threadIdx.x;

  vf4 A[4], Bv[4], C[4], Dv[4];
  #pragma unroll
  for (int t = 0; t < 4; ++t) {
    const int i = base + t * 256;
    A[t]  = __builtin_nontemporal_load(&pmu[i]);
    Bv[t] = __builtin_nontemporal_load(&plv[i]);
    C[t]  = __builtin_nontemporal_load(&qmu[i]);
    Dv[t] = __builtin_nontemporal_load(&qlv[i]);
  }

  float acc = 0.0f;
  #pragma unroll
  for (int t = 0; t < 4; ++t)
    acc += kl4(A[t], Bv[t], C[t], Dv[t]);

  const float blocksum = block_reduce_256(acc);
  if (threadIdx.x == 0) partials[blockIdx.x] = blocksum;
}

// Stage 2: single block folds nparts partials, scales, writes the scalar.
__global__ __launch_bounds__(256) void kl_final_kernel(
    const float* __restrict__ partials, float* __restrict__ out,
    int nparts, float scale) {
  float acc = 0.0f;
  for (int i = threadIdx.x; i < nparts; i += 256) acc += partials[i];
  const float total = block_reduce_256(acc);
  if (threadIdx.x == 0) out[0] = total * scale;
}

extern "C" void kernel_launch(void* const* d_in, const int* in_sizes, int n_in,
                              void* d_out, int out_size, void* d_ws, size_t ws_size,
                              hipStream_t stream) {
  const vf4* pmu = (const vf4*)d_in[0];
  const vf4* plv = (const vf4*)d_in[1];
  const vf4* qmu = (const vf4*)d_in[2];
  const vf4* qlv = (const vf4*)d_in[3];
  float* out = (float*)d_out;
  float* partials = (float*)d_ws;       // 2048 floats = 8 KB scratch

  const int B = 16384;
  const float scale = 0.5f / (float)B;

  const int block = 256;
  const int grid = 2048;                // 2048 windows x 1024 vf4 = 2M vf4/array
  kl_partial_kernel<<<grid, block, 0, stream>>>(pmu, plv, qmu, qlv, partials);
  kl_final_kernel<<<1, block, 0, stream>>>(partials, out, grid, scale);
}